// Round 1
// baseline (4173.196 us; speedup 1.0000x reference)
//
#include <hip/hip_runtime.h>
#include <hip/hip_bf16.h>
#include <stdint.h>

#define B_ 4
#define S_ 2048
#define H_ 1024
#define I_ 4096
#define E_ 8
#define CAP 640
#define NTOK (B_*S_)            // 8192
#define NBE  (B_*E_)            // 32
#define NROW (NBE*CAP)          // 20480

// workspace layout (bytes)
#define OFF_LOGITS   0u                         // 65536 f32  [B][E][S]
#define OFF_TOPKI    (OFF_LOGITS + 65536u*4u)   // 20480 int
#define OFF_TOPKW    (OFF_TOPKI  + 20480u*4u)   // 20480 f32
#define OFF_COUNTS   (OFF_TOPKW  + 20480u*4u)   // 8192 f32
#define OFF_SCAL     (OFF_COUNTS + 8192u*4u)    // 16 f32: [0]=z_sum, [1..8]=usage_sum
#define OFF_MID      (1u<<20)                   // 20480*4096 bf16 (167.8 MB)

static __device__ __forceinline__ unsigned short f32_to_bf16_rne(float v) {
    unsigned u = __float_as_uint(v);
    unsigned r = (u + 0x7FFFu + ((u >> 16) & 1u)) >> 16;
    return (unsigned short)r;
}
static __device__ __forceinline__ float bf16_bits_to_f32(unsigned short h) {
    return __uint_as_float(((unsigned)h) << 16);
}

// ---------------------------------------------------------------- router ----
__global__ void k_router(const float* __restrict__ x, const float* __restrict__ rw,
                         float* __restrict__ logits, float* __restrict__ scal) {
    __shared__ float rwt[E_ * H_];            // transposed router weights [e][h]
    __shared__ float part[4][9];
    int tid = threadIdx.x;
    for (int i = tid; i < E_ * H_; i += 256) {
        int h = i >> 3, e = i & 7;
        rwt[e * H_ + h] = rw[i];
    }
    __syncthreads();
    int w = tid >> 6, lane = tid & 63;
    int t = blockIdx.x * 4 + w;               // token id in [0, 8192)
    const float* xr = x + (size_t)t * H_;
    float acc[E_];
#pragma unroll
    for (int e = 0; e < E_; ++e) acc[e] = 0.f;
    for (int it = 0; it < H_ / 64; ++it) {
        int h = lane + it * 64;
        float xv = xr[h];
#pragma unroll
        for (int e = 0; e < E_; ++e) acc[e] += xv * rwt[e * H_ + h];
    }
#pragma unroll
    for (int off = 32; off > 0; off >>= 1)
#pragma unroll
        for (int e = 0; e < E_; ++e) acc[e] += __shfl_down(acc[e], off);
    if (lane == 0) {
        int b = t >> 11, s = t & 2047;
        float m = acc[0];
#pragma unroll
        for (int e = 1; e < E_; ++e) m = fmaxf(m, acc[e]);
        float z = 0.f, ps = 0.f;
        float p[E_];
#pragma unroll
        for (int e = 0; e < E_; ++e) {
            logits[(size_t)((b << 3) + e) * S_ + s] = acc[e];
            z += acc[e] * acc[e];
            p[e] = expf(acc[e] - m);
            ps += p[e];
        }
        part[w][0] = z;
#pragma unroll
        for (int e = 0; e < E_; ++e) part[w][1 + e] = p[e] / ps;
    }
    __syncthreads();
    if (tid < 9) {
        float v = part[0][tid] + part[1][tid] + part[2][tid] + part[3][tid];
        atomicAdd(&scal[tid], v);
    }
}

// ----------------------------------------------------------------- top-k ----
// One block per (b,e): bitonic sort of 2048 (value,idx) packed keys, descending,
// tie-break = lower index first (matches jax.lax.top_k).
__global__ void __launch_bounds__(1024) k_topk(const float* __restrict__ logits,
                                               int* __restrict__ tki,
                                               float* __restrict__ tkw,
                                               float* __restrict__ counts) {
    int be = blockIdx.x;
    const float* row = logits + (size_t)be * S_;
    __shared__ unsigned long long keys[S_];
    __shared__ float wpart[16];
    __shared__ float stot;
    int tid = threadIdx.x;
    for (int i = tid; i < S_; i += 1024) {
        unsigned u = __float_as_uint(row[i]);
        u = (u & 0x80000000u) ? ~u : (u | 0x80000000u);   // order-preserving flip
        keys[i] = ((unsigned long long)u << 32) | (unsigned)(~i);
    }
    __syncthreads();
    for (int k = 2; k <= S_; k <<= 1) {
        for (int j = k >> 1; j > 0; j >>= 1) {
#pragma unroll
            for (int base = 0; base < S_; base += 1024) {
                int i = base + tid;
                int ixj = i ^ j;
                if (ixj > i) {
                    unsigned long long a = keys[i], b = keys[ixj];
                    bool up = ((i & k) == 0);
                    bool sw = up ? (a < b) : (a > b);   // global descending
                    if (sw) { keys[i] = b; keys[ixj] = a; }
                }
            }
            __syncthreads();
        }
    }
    // softmax over top CAP values
    int idx0 = (int)(~(unsigned)(keys[0] & 0xFFFFFFFFu));
    float vmax = row[idx0];
    int myidx = 0; float ex = 0.f;
    if (tid < CAP) {
        myidx = (int)(~(unsigned)(keys[tid] & 0xFFFFFFFFu));
        ex = expf(row[myidx] - vmax);
    }
    float v = ex;
#pragma unroll
    for (int off = 32; off > 0; off >>= 1) v += __shfl_down(v, off);
    if ((tid & 63) == 0) wpart[tid >> 6] = v;
    __syncthreads();
    if (tid == 0) {
        float s = 0.f;
#pragma unroll
        for (int i = 0; i < 16; ++i) s += wpart[i];
        stot = s;
    }
    __syncthreads();
    if (tid < CAP) {
        tki[be * CAP + tid] = myidx;
        tkw[be * CAP + tid] = ex / stot;
        atomicAdd(&counts[(be >> 3) * S_ + myidx], 1.0f);
    }
}

// ------------------------------------------------------- GEMM1 (+SiLU) ------
// mid[row, :] = silu(x[gather(row), :] @ w1[e]),  row-tiles of 128, col-tiles of 128
__global__ void __launch_bounds__(256) k_gemm1(const float* __restrict__ x,
                                               const float* __restrict__ w1,
                                               const int* __restrict__ tki,
                                               unsigned short* __restrict__ mid) {
    int rt = blockIdx.x;              // 0..159
    int ct = blockIdx.y;              // 0..31
    int be = rt / 5, rq = rt % 5;
    int b = be >> 3, e = be & 7;
    const float* w1e = w1 + (size_t)e * H_ * I_;
    __shared__ float As[128][17];
    __shared__ float Bs[16][128];
    __shared__ int   toks[128];
    int tid = threadIdx.x;
    if (tid < 128) toks[tid] = tki[be * CAP + rq * 128 + tid];
    __syncthreads();
    int ty = tid >> 4, tx = tid & 15;
    float acc[8][8];
#pragma unroll
    for (int i = 0; i < 8; ++i)
#pragma unroll
        for (int j = 0; j < 8; ++j) acc[i][j] = 0.f;
    int col0 = ct * 128;
    for (int k0 = 0; k0 < H_; k0 += 16) {
#pragma unroll
        for (int q = 0; q < 2; ++q) {
            int fid = tid * 2 + q;
            int r = fid >> 2, kq = fid & 3;
            float4 av = *(const float4*)(x + ((size_t)b * S_ + toks[r]) * H_ + k0 + kq * 4);
            As[r][kq * 4 + 0] = av.x; As[r][kq * 4 + 1] = av.y;
            As[r][kq * 4 + 2] = av.z; As[r][kq * 4 + 3] = av.w;
            int kk = fid >> 5, cq = fid & 31;
            float4 bv = *(const float4*)(w1e + (size_t)(k0 + kk) * I_ + col0 + cq * 4);
            *(float4*)&Bs[kk][cq * 4] = bv;
        }
        __syncthreads();
#pragma unroll
        for (int kk = 0; kk < 16; ++kk) {
            float a[8], bb[8];
#pragma unroll
            for (int ii = 0; ii < 4; ++ii) {
                a[ii]     = As[ty * 4 + ii][kk];
                a[4 + ii] = As[64 + ty * 4 + ii][kk];
            }
            float4 b0 = *(float4*)&Bs[kk][tx * 4];
            float4 b1 = *(float4*)&Bs[kk][64 + tx * 4];
            bb[0] = b0.x; bb[1] = b0.y; bb[2] = b0.z; bb[3] = b0.w;
            bb[4] = b1.x; bb[5] = b1.y; bb[6] = b1.z; bb[7] = b1.w;
#pragma unroll
            for (int i = 0; i < 8; ++i)
#pragma unroll
                for (int j = 0; j < 8; ++j) acc[i][j] += a[i] * bb[j];
        }
        __syncthreads();
    }
    size_t rowbase = (size_t)be * CAP + rq * 128;
#pragma unroll
    for (int i = 0; i < 8; ++i) {
        int r = (i < 4) ? (ty * 4 + i) : (64 + ty * 4 + (i - 4));
        size_t gr = (rowbase + r) * I_ + col0;
#pragma unroll
        for (int jh = 0; jh < 2; ++jh) {
            int cbase = jh * 64 + tx * 4;
            ushort4 pk;
            float v0 = acc[i][jh * 4 + 0], v1 = acc[i][jh * 4 + 1];
            float v2 = acc[i][jh * 4 + 2], v3 = acc[i][jh * 4 + 3];
            v0 = v0 / (1.f + expf(-v0)); v1 = v1 / (1.f + expf(-v1));
            v2 = v2 / (1.f + expf(-v2)); v3 = v3 / (1.f + expf(-v3));
            pk.x = f32_to_bf16_rne(v0); pk.y = f32_to_bf16_rne(v1);
            pk.z = f32_to_bf16_rne(v2); pk.w = f32_to_bf16_rne(v3);
            *(ushort4*)(mid + gr + cbase) = pk;
        }
    }
}

// ----------------------------------------------- GEMM2 + weighted scatter ---
__global__ void __launch_bounds__(256) k_gemm2(const unsigned short* __restrict__ mid,
                                               const float* __restrict__ w2,
                                               const int* __restrict__ tki,
                                               const float* __restrict__ tkw,
                                               float* __restrict__ out) {
    int rt = blockIdx.x;              // 0..159
    int ct = blockIdx.y;              // 0..7
    int be = rt / 5, rq = rt % 5;
    int b = be >> 3, e = be & 7;
    const float* w2e = w2 + (size_t)e * I_ * H_;
    __shared__ float As[128][17];
    __shared__ float Bs[16][128];
    __shared__ int   toks[128];
    __shared__ float wts[128];
    int tid = threadIdx.x;
    if (tid < 128) {
        toks[tid] = tki[be * CAP + rq * 128 + tid];
        wts[tid]  = tkw[be * CAP + rq * 128 + tid];
    }
    __syncthreads();
    int ty = tid >> 4, tx = tid & 15;
    float acc[8][8];
#pragma unroll
    for (int i = 0; i < 8; ++i)
#pragma unroll
        for (int j = 0; j < 8; ++j) acc[i][j] = 0.f;
    int col0 = ct * 128;
    size_t rowbase = (size_t)be * CAP + rq * 128;
    for (int k0 = 0; k0 < I_; k0 += 16) {
#pragma unroll
        for (int q = 0; q < 2; ++q) {
            int fid = tid * 2 + q;
            int r = fid >> 2, kq = fid & 3;
            ushort4 av = *(const ushort4*)(mid + (rowbase + r) * I_ + k0 + kq * 4);
            As[r][kq * 4 + 0] = bf16_bits_to_f32(av.x);
            As[r][kq * 4 + 1] = bf16_bits_to_f32(av.y);
            As[r][kq * 4 + 2] = bf16_bits_to_f32(av.z);
            As[r][kq * 4 + 3] = bf16_bits_to_f32(av.w);
            int kk = fid >> 5, cq = fid & 31;
            float4 bv = *(const float4*)(w2e + (size_t)(k0 + kk) * H_ + col0 + cq * 4);
            *(float4*)&Bs[kk][cq * 4] = bv;
        }
        __syncthreads();
#pragma unroll
        for (int kk = 0; kk < 16; ++kk) {
            float a[8], bb[8];
#pragma unroll
            for (int ii = 0; ii < 4; ++ii) {
                a[ii]     = As[ty * 4 + ii][kk];
                a[4 + ii] = As[64 + ty * 4 + ii][kk];
            }
            float4 b0 = *(float4*)&Bs[kk][tx * 4];
            float4 b1 = *(float4*)&Bs[kk][64 + tx * 4];
            bb[0] = b0.x; bb[1] = b0.y; bb[2] = b0.z; bb[3] = b0.w;
            bb[4] = b1.x; bb[5] = b1.y; bb[6] = b1.z; bb[7] = b1.w;
#pragma unroll
            for (int i = 0; i < 8; ++i)
#pragma unroll
                for (int j = 0; j < 8; ++j) acc[i][j] += a[i] * bb[j];
        }
        __syncthreads();
    }
#pragma unroll
    for (int i = 0; i < 8; ++i) {
        int r = (i < 4) ? (ty * 4 + i) : (64 + ty * 4 + (i - 4));
        int token = toks[r];
        float wgt = wts[r];
        float* orow = out + ((size_t)b * S_ + token) * H_ + col0;
#pragma unroll
        for (int jh = 0; jh < 2; ++jh) {
            int cbase = jh * 64 + tx * 4;
#pragma unroll
            for (int q = 0; q < 4; ++q) {
                atomicAdd(&orow[cbase + q], acc[i][jh * 4 + q] * wgt);
            }
        }
    }
}

// ------------------------------------------------- normalize + loss ---------
__global__ void k_final(float* __restrict__ out, const float* __restrict__ counts,
                        const float* __restrict__ scal, float* __restrict__ loss_out) {
    size_t gid = (size_t)blockIdx.x * 256 + threadIdx.x;   // one float4 each
    int tok = (int)(gid >> 8);                             // 256 float4 per token
    float c = fmaxf(counts[tok], 1.0f);
    float4* o4 = (float4*)out;
    float4 v = o4[gid];
    v.x /= c; v.y /= c; v.z /= c; v.w /= c;
    o4[gid] = v;
    if (gid == 0) {
        float z = scal[0] / (float)(NTOK * E_);
        float aux = 0.f;
#pragma unroll
        for (int e = 0; e < E_; ++e) {
            float u = scal[1 + e] / (float)NTOK - 0.125f;
            aux += u * u;
        }
        loss_out[0] = 0.01f * aux + 0.001f * z;
    }
}

// ----------------------------------------------------------------------------
extern "C" void kernel_launch(void* const* d_in, const int* in_sizes, int n_in,
                              void* d_out, int out_size, void* d_ws, size_t ws_size,
                              hipStream_t stream) {
    const float* x  = (const float*)d_in[0];
    const float* rw = (const float*)d_in[1];
    const float* w1 = (const float*)d_in[2];
    const float* w2 = (const float*)d_in[3];
    float* out = (float*)d_out;
    char* ws = (char*)d_ws;

    float* logits = (float*)(ws + OFF_LOGITS);
    int*   tki    = (int*)(ws + OFF_TOPKI);
    float* tkw    = (float*)(ws + OFF_TOPKW);
    float* counts = (float*)(ws + OFF_COUNTS);
    float* scal   = (float*)(ws + OFF_SCAL);
    unsigned short* mid = (unsigned short*)(ws + OFF_MID);

    // zero: counts + scalars, and the output accumulator
    hipMemsetAsync(ws + OFF_COUNTS, 0, 8192u * 4u + 64u, stream);
    hipMemsetAsync(d_out, 0, (size_t)out_size * sizeof(float), stream);

    k_router<<<NTOK / 4, 256, 0, stream>>>(x, rw, logits, scal);
    k_topk<<<NBE, 1024, 0, stream>>>(logits, tki, tkw, counts);
    k_gemm1<<<dim3(NBE * 5, I_ / 128), 256, 0, stream>>>(x, w1, tki, mid);
    k_gemm2<<<dim3(NBE * 5, H_ / 128), 256, 0, stream>>>(mid, w2, tki, tkw, out);
    k_final<<<(NTOK * H_ / 4) / 256, 256, 0, stream>>>(out, counts, scal,
                                                       out + (size_t)NTOK * H_);
}

// Round 2
// 711.879 us; speedup vs baseline: 5.8622x; 5.8622x over previous
//
#include <hip/hip_runtime.h>
#include <hip/hip_bf16.h>
#include <stdint.h>

#define B_ 4
#define S_ 2048
#define H_ 1024
#define I_ 4096
#define E_ 8
#define CAP 640
#define NTOK (B_*S_)            // 8192
#define NBE  (B_*E_)            // 32

typedef _Float16 f16;
typedef f16 f16x8 __attribute__((ext_vector_type(8)));
typedef float f32x4 __attribute__((ext_vector_type(4)));

// workspace layout (bytes)
#define OFF_LOGITS 0u                          // 65536 f32
#define OFF_TOPKI  (256u*1024u)                // 20480 int
#define OFF_TOPKW  (OFF_TOPKI + 128u*1024u)    // 20480 f32
#define OFF_COUNTS (OFF_TOPKW + 128u*1024u)    // 8192 f32
#define OFF_SCAL   (OFF_COUNTS + 64u*1024u)    // 16 f32
#define OFF_XH     (1u<<20)                    // 8192*1024 f16   (16.8 MB)
#define OFF_WT     (18u<<20)                   // 8*4096*1024 f16 (67.1 MB) — w1t then w2t (reused)
#define OFF_MID    (86u<<20)                   // 20480*4096 f16  (167.8 MB) → high-water ~254 MB

__device__ __forceinline__ void gl_lds16(const void* g, void* l) {
    __builtin_amdgcn_global_load_lds(
        (const __attribute__((address_space(1))) uint32_t*)g,
        (__attribute__((address_space(3))) uint32_t*)l, 16, 0, 0);
}

// ---------------------------------------------------------------- router ----
__global__ void k_router(const float* __restrict__ x, const float* __restrict__ rw,
                         float* __restrict__ logits, float* __restrict__ scal) {
    __shared__ float rwt[E_ * H_];
    __shared__ float part[4][9];
    int tid = threadIdx.x;
    for (int i = tid; i < E_ * H_; i += 256) {
        int h = i >> 3, e = i & 7;
        rwt[e * H_ + h] = rw[i];
    }
    __syncthreads();
    int w = tid >> 6, lane = tid & 63;
    int t = blockIdx.x * 4 + w;
    const float* xr = x + (size_t)t * H_;
    float acc[E_];
#pragma unroll
    for (int e = 0; e < E_; ++e) acc[e] = 0.f;
    for (int it = 0; it < H_ / 64; ++it) {
        int h = lane + it * 64;
        float xv = xr[h];
#pragma unroll
        for (int e = 0; e < E_; ++e) acc[e] += xv * rwt[e * H_ + h];
    }
#pragma unroll
    for (int off = 32; off > 0; off >>= 1)
#pragma unroll
        for (int e = 0; e < E_; ++e) acc[e] += __shfl_down(acc[e], off);
    if (lane == 0) {
        int b = t >> 11, s = t & 2047;
        float m = acc[0];
#pragma unroll
        for (int e = 1; e < E_; ++e) m = fmaxf(m, acc[e]);
        float z = 0.f, ps = 0.f;
        float p[E_];
#pragma unroll
        for (int e = 0; e < E_; ++e) {
            logits[(size_t)((b << 3) + e) * S_ + s] = acc[e];
            z += acc[e] * acc[e];
            p[e] = expf(acc[e] - m);
            ps += p[e];
        }
        part[w][0] = z;
#pragma unroll
        for (int e = 0; e < E_; ++e) part[w][1 + e] = p[e] / ps;
    }
    __syncthreads();
    if (tid < 9) {
        float v = part[0][tid] + part[1][tid] + part[2][tid] + part[3][tid];
        atomicAdd(&scal[tid], v);
    }
}

// ----------------------------------------------------------------- top-k ----
__global__ void __launch_bounds__(1024) k_topk(const float* __restrict__ logits,
                                               int* __restrict__ tki,
                                               float* __restrict__ tkw,
                                               float* __restrict__ counts) {
    int be = blockIdx.x;
    const float* row = logits + (size_t)be * S_;
    __shared__ unsigned long long keys[S_];
    __shared__ float wpart[16];
    __shared__ float stot;
    int tid = threadIdx.x;
    for (int i = tid; i < S_; i += 1024) {
        unsigned u = __float_as_uint(row[i]);
        u = (u & 0x80000000u) ? ~u : (u | 0x80000000u);
        keys[i] = ((unsigned long long)u << 32) | (unsigned)(~i);
    }
    __syncthreads();
    for (int k = 2; k <= S_; k <<= 1) {
        for (int j = k >> 1; j > 0; j >>= 1) {
#pragma unroll
            for (int base = 0; base < S_; base += 1024) {
                int i = base + tid;
                int ixj = i ^ j;
                if (ixj > i) {
                    unsigned long long a = keys[i], b = keys[ixj];
                    bool up = ((i & k) == 0);
                    bool sw = up ? (a < b) : (a > b);
                    if (sw) { keys[i] = b; keys[ixj] = a; }
                }
            }
            __syncthreads();
        }
    }
    int idx0 = (int)(~(unsigned)(keys[0] & 0xFFFFFFFFu));
    float vmax = row[idx0];
    int myidx = 0; float ex = 0.f;
    if (tid < CAP) {
        myidx = (int)(~(unsigned)(keys[tid] & 0xFFFFFFFFu));
        ex = expf(row[myidx] - vmax);
    }
    float v = ex;
#pragma unroll
    for (int off = 32; off > 0; off >>= 1) v += __shfl_down(v, off);
    if ((tid & 63) == 0) wpart[tid >> 6] = v;
    __syncthreads();
    if (tid == 0) {
        float s = 0.f;
#pragma unroll
        for (int i = 0; i < 16; ++i) s += wpart[i];
        stot = s;
    }
    __syncthreads();
    if (tid < CAP) {
        tki[be * CAP + tid] = myidx;
        tkw[be * CAP + tid] = ex / stot;
        atomicAdd(&counts[(be >> 3) * S_ + myidx], 1.0f);
    }
}

// ------------------------------------------------------------ conversions ---
__global__ void k_cvt_x(const float* __restrict__ in, f16* __restrict__ out) {
    size_t i = ((size_t)blockIdx.x * 256 + threadIdx.x) << 3;
    float4 a = *(const float4*)(in + i);
    float4 b = *(const float4*)(in + i + 4);
    f16x8 o = { (f16)a.x, (f16)a.y, (f16)a.z, (f16)a.w,
                (f16)b.x, (f16)b.y, (f16)b.z, (f16)b.w };
    *(f16x8*)(out + i) = o;
}

// in: [E][R][C] f32 → out: [E][C][R] f16
template<int R, int C>
__global__ void __launch_bounds__(256) k_transpose(const float* __restrict__ in,
                                                   f16* __restrict__ out) {
    __shared__ f16 t[64][68];
    int e = blockIdx.z;
    const float* ine = in + (size_t)e * R * C;
    f16* oute = out + (size_t)e * R * C;
    int c0 = blockIdx.x << 6, r0 = blockIdx.y << 6;
    int tx = threadIdx.x & 15, ty = threadIdx.x >> 4;
#pragma unroll
    for (int p = 0; p < 4; ++p) {
        int r = ty + p * 16;
        float4 v = *(const float4*)(ine + (size_t)(r0 + r) * C + c0 + tx * 4);
        t[tx * 4 + 0][r] = (f16)v.x;
        t[tx * 4 + 1][r] = (f16)v.y;
        t[tx * 4 + 2][r] = (f16)v.z;
        t[tx * 4 + 3][r] = (f16)v.w;
    }
    __syncthreads();
#pragma unroll
    for (int p = 0; p < 4; ++p) {
        int c = ty + p * 16;
        *(ushort4*)(oute + (size_t)(c0 + c) * R + r0 + tx * 4) =
            *(const ushort4*)&t[c][tx * 4];
    }
}

// ---------------------------------------------------------- GEMM1 (+SiLU) ---
// mid[row,:] = silu(xh[gather(row),:] @ w1t^T), 128x128 tile, BK=32, f16 MFMA
__global__ void __launch_bounds__(256) k_gemm1(const f16* __restrict__ xh,
                                               const f16* __restrict__ w1t,
                                               const int* __restrict__ tki,
                                               f16* __restrict__ mid) {
    __shared__ f16 Al[4096];   // [128 m][32 k], 16B-chunk swizzled
    __shared__ f16 Bl[4096];   // [128 n][32 k], 16B-chunk swizzled
    int rt = blockIdx.x, ct = blockIdx.y;
    int be = rt / 5, rq = rt - be * 5;
    int b = be >> 3, e = be & 7;
    int tid = threadIdx.x;
    int w = tid >> 6, l = tid & 63;
    // staging: lane covers (row = c*64 + w*16 + l/4, 16B slot = l&3);
    // swizzle: slot s of row r holds global k-chunk s ^ ((r>>2)&3); (r>>2)&3 == l>>4
    int chunk = (l & 3) ^ (l >> 4);
    const f16* asrc[2];
    const f16* bsrc[2];
    const f16* w1e = w1t + ((size_t)e << 22);
    int n0 = ct << 7;
#pragma unroll
    for (int c = 0; c < 2; ++c) {
        int row = c * 64 + w * 16 + (l >> 2);
        int tok = tki[be * CAP + rq * 128 + row];
        asrc[c] = xh + (((size_t)(b * S_ + tok)) << 10) + (chunk << 3);
        bsrc[c] = w1e + (((size_t)(n0 + row)) << 10) + (chunk << 3);
    }
    f16* adst[2] = { Al + w * 512, Al + 2048 + w * 512 };   // wave-uniform
    f16* bdst[2] = { Bl + w * 512, Bl + 2048 + w * 512 };
    int wm = w >> 1, wn = w & 1;
    int fr = l & 15;
    int slot = (l >> 4) ^ ((l >> 2) & 3);    // read slot: g ^ ((r>>2)&3)
    const f16* arow[4];
    const f16* brow[4];
#pragma unroll
    for (int m = 0; m < 4; ++m) {
        arow[m] = Al + (wm * 64 + m * 16 + fr) * 32 + slot * 8;
        brow[m] = Bl + (wn * 64 + m * 16 + fr) * 32 + slot * 8;
    }
    f32x4 acc[4][4];
#pragma unroll
    for (int m = 0; m < 4; ++m)
#pragma unroll
        for (int n = 0; n < 4; ++n) acc[m][n] = (f32x4){0.f, 0.f, 0.f, 0.f};

    for (int ks = 0; ks < H_ / 32; ++ks) {
        gl_lds16(asrc[0], adst[0]); gl_lds16(asrc[1], adst[1]);
        gl_lds16(bsrc[0], bdst[0]); gl_lds16(bsrc[1], bdst[1]);
        asrc[0] += 32; asrc[1] += 32; bsrc[0] += 32; bsrc[1] += 32;
        __syncthreads();
        f16x8 af[4], bf[4];
#pragma unroll
        for (int m = 0; m < 4; ++m) af[m] = *(const f16x8*)arow[m];
#pragma unroll
        for (int n = 0; n < 4; ++n) bf[n] = *(const f16x8*)brow[n];
#pragma unroll
        for (int m = 0; m < 4; ++m)
#pragma unroll
            for (int n = 0; n < 4; ++n)
                acc[m][n] = __builtin_amdgcn_mfma_f32_16x16x32_f16(af[m], bf[n], acc[m][n], 0, 0, 0);
        __syncthreads();
    }
    size_t rowbase = (size_t)be * CAP + rq * 128;
    int rq4 = (l >> 4) << 2;
#pragma unroll
    for (int m = 0; m < 4; ++m)
#pragma unroll
        for (int n = 0; n < 4; ++n)
#pragma unroll
            for (int q = 0; q < 4; ++q) {
                float v = acc[m][n][q];
                v = v / (1.f + expf(-v));
                int rr = wm * 64 + m * 16 + rq4 + q;
                int cc = n0 + wn * 64 + n * 16 + fr;
                mid[(rowbase + rr) * (size_t)I_ + cc] = (f16)v;
            }
}

// ------------------------------------------- GEMM2 + weighted atomic scatter
__global__ void __launch_bounds__(256) k_gemm2(const f16* __restrict__ mid,
                                               const f16* __restrict__ w2t,
                                               const int* __restrict__ tki,
                                               const float* __restrict__ tkw,
                                               float* __restrict__ out) {
    __shared__ f16 Al[4096];
    __shared__ f16 Bl[4096];
    __shared__ int   toksS[128];
    __shared__ float wtsS[128];
    int rt = blockIdx.x, ct = blockIdx.y;
    int be = rt / 5, rq = rt - be * 5;
    int b = be >> 3, e = be & 7;
    int tid = threadIdx.x;
    int w = tid >> 6, l = tid & 63;
    if (tid < 128) {
        toksS[tid] = tki[be * CAP + rq * 128 + tid];
        wtsS[tid]  = tkw[be * CAP + rq * 128 + tid];
    }
    int chunk = (l & 3) ^ (l >> 4);
    size_t rowbase = (size_t)be * CAP + rq * 128;
    const f16* asrc[2];
    const f16* bsrc[2];
    const f16* w2e = w2t + ((size_t)e << 22);
    int n0 = ct << 7;
#pragma unroll
    for (int c = 0; c < 2; ++c) {
        int row = c * 64 + w * 16 + (l >> 2);
        asrc[c] = mid + (rowbase + row) * (size_t)I_ + (chunk << 3);
        bsrc[c] = w2e + (((size_t)(n0 + row)) << 12) + (chunk << 3);
    }
    f16* adst[2] = { Al + w * 512, Al + 2048 + w * 512 };
    f16* bdst[2] = { Bl + w * 512, Bl + 2048 + w * 512 };
    int wm = w >> 1, wn = w & 1;
    int fr = l & 15;
    int slot = (l >> 4) ^ ((l >> 2) & 3);
    const f16* arow[4];
    const f16* brow[4];
#pragma unroll
    for (int m = 0; m < 4; ++m) {
        arow[m] = Al + (wm * 64 + m * 16 + fr) * 32 + slot * 8;
        brow[m] = Bl + (wn * 64 + m * 16 + fr) * 32 + slot * 8;
    }
    f32x4 acc[4][4];
#pragma unroll
    for (int m = 0; m < 4; ++m)
#pragma unroll
        for (int n = 0; n < 4; ++n) acc[m][n] = (f32x4){0.f, 0.f, 0.f, 0.f};

    for (int ks = 0; ks < I_ / 32; ++ks) {
        gl_lds16(asrc[0], adst[0]); gl_lds16(asrc[1], adst[1]);
        gl_lds16(bsrc[0], bdst[0]); gl_lds16(bsrc[1], bdst[1]);
        asrc[0] += 32; asrc[1] += 32; bsrc[0] += 32; bsrc[1] += 32;
        __syncthreads();
        f16x8 af[4], bf[4];
#pragma unroll
        for (int m = 0; m < 4; ++m) af[m] = *(const f16x8*)arow[m];
#pragma unroll
        for (int n = 0; n < 4; ++n) bf[n] = *(const f16x8*)brow[n];
#pragma unroll
        for (int m = 0; m < 4; ++m)
#pragma unroll
            for (int n = 0; n < 4; ++n)
                acc[m][n] = __builtin_amdgcn_mfma_f32_16x16x32_f16(af[m], bf[n], acc[m][n], 0, 0, 0);
        __syncthreads();
    }
    int rq4 = (l >> 4) << 2;
#pragma unroll
    for (int m = 0; m < 4; ++m)
#pragma unroll
        for (int n = 0; n < 4; ++n)
#pragma unroll
            for (int q = 0; q < 4; ++q) {
                int rr = wm * 64 + m * 16 + rq4 + q;
                int cc = n0 + wn * 64 + n * 16 + fr;
                int token = toksS[rr];
                float wgt = wtsS[rr];
                atomicAdd(&out[((size_t)(b * S_ + token) << 10) + cc],
                          acc[m][n][q] * wgt);
            }
}

// ------------------------------------------------- normalize + loss ---------
__global__ void k_final(float* __restrict__ out, const float* __restrict__ counts,
                        const float* __restrict__ scal, float* __restrict__ loss_out) {
    size_t gid = (size_t)blockIdx.x * 256 + threadIdx.x;
    int tok = (int)(gid >> 8);
    float c = fmaxf(counts[tok], 1.0f);
    float4* o4 = (float4*)out;
    float4 v = o4[gid];
    v.x /= c; v.y /= c; v.z /= c; v.w /= c;
    o4[gid] = v;
    if (gid == 0) {
        float z = scal[0] / (float)(NTOK * E_);
        float aux = 0.f;
#pragma unroll
        for (int e = 0; e < E_; ++e) {
            float u = scal[1 + e] / (float)NTOK - 0.125f;
            aux += u * u;
        }
        loss_out[0] = 0.01f * aux + 0.001f * z;
    }
}

// ----------------------------------------------------------------------------
extern "C" void kernel_launch(void* const* d_in, const int* in_sizes, int n_in,
                              void* d_out, int out_size, void* d_ws, size_t ws_size,
                              hipStream_t stream) {
    const float* x  = (const float*)d_in[0];
    const float* rw = (const float*)d_in[1];
    const float* w1 = (const float*)d_in[2];
    const float* w2 = (const float*)d_in[3];
    float* out = (float*)d_out;
    char* ws = (char*)d_ws;

    float* logits = (float*)(ws + OFF_LOGITS);
    int*   tki    = (int*)(ws + OFF_TOPKI);
    float* tkw    = (float*)(ws + OFF_TOPKW);
    float* counts = (float*)(ws + OFF_COUNTS);
    float* scal   = (float*)(ws + OFF_SCAL);
    f16*   xh     = (f16*)(ws + OFF_XH);
    f16*   wt     = (f16*)(ws + OFF_WT);     // w1t, then reused as w2t
    f16*   mid    = (f16*)(ws + OFF_MID);

    hipMemsetAsync(ws + OFF_COUNTS, 0, 64u * 1024u + 64u, stream);
    hipMemsetAsync(d_out, 0, (size_t)out_size * sizeof(float), stream);

    k_cvt_x<<<NTOK * H_ / 8 / 256, 256, 0, stream>>>(x, xh);
    k_transpose<H_, I_><<<dim3(I_ / 64, H_ / 64, E_), 256, 0, stream>>>(w1, wt);
    k_router<<<NTOK / 4, 256, 0, stream>>>(x, rw, logits, scal);
    k_topk<<<NBE, 1024, 0, stream>>>(logits, tki, tkw, counts);
    k_gemm1<<<dim3(NBE * 5, I_ / 128), 256, 0, stream>>>(xh, wt, tki, mid);
    // reuse WT region for w2t (stream-ordered after gemm1 finished reading w1t)
    k_transpose<I_, H_><<<dim3(H_ / 64, I_ / 64, E_), 256, 0, stream>>>(w2, wt);
    k_gemm2<<<dim3(NBE * 5, H_ / 128), 256, 0, stream>>>(mid, wt, tki, tkw, out);
    k_final<<<(NTOK * H_ / 4) / 256, 256, 0, stream>>>(out, counts, scal,
                                                       out + (size_t)NTOK * H_);
}